// Round 4
// baseline (3349.056 us; speedup 1.0000x reference)
//
#include <hip/hip_runtime.h>
#include <hip/hip_bf16.h>

#define N_PTS  65536
#define DMODEL 256
#define MSAMP  1024

#define NW  64   // FPS waves = single-wave workgroups (all co-resident)
#define FPT 16   // points per lane: 65536 / (64 * 64)

typedef short bf16x8_t __attribute__((ext_vector_type(8)));
typedef float f32x4_t  __attribute__((ext_vector_type(4)));

__device__ __forceinline__ short f2bs(float f) {
    __hip_bfloat16 h = __float2bfloat16(f);   // RNE
    return *reinterpret_cast<short*>(&h);
}

// load 8 consecutive f32 and convert to a bf16x8 MFMA fragment
__device__ __forceinline__ bf16x8_t cvt8(const float* p) {
    f32x4_t a = *(const f32x4_t*)(p);
    f32x4_t b = *(const f32x4_t*)(p + 4);
    bf16x8_t r;
#pragma unroll
    for (int i = 0; i < 4; i++) {
        r[i]     = f2bs(a[i]);
        r[i + 4] = f2bs(b[i]);
    }
    return r;
}

// ---------------------------------------------------------------------------
// Fused FPS + q-projection-in-shadow.
//   blocks [0, NW):    FPS, one wave each (lanes 64-255 exit immediately).
//   blocks [NW, ...):  q = feat @ Wq^T + bq -> bf16 qb (runs under FPS shadow).
//
// FPS per iteration: in-register min-update + argmax, 6-step shfl butterfly
// (u64 packs compared as positive f64 bit patterns), ONE u64 slot store per
// wave (relaxed, agent scope), poll = one tagged u64 load per lane, butterfly,
// winner coords re-fetched from read-only xyz (L2-resident, never stale).
// Slots double-buffered by iteration parity. Exact numpy arithmetic
// (per-op RN f32, ((dx^2+dy^2)+dz^2)) and first-index tie-break.
// ---------------------------------------------------------------------------
__global__ __launch_bounds__(256) void fps_q_kernel(
    const float*        __restrict__ xyz,      // (N,3) f32
    unsigned long long* __restrict__ slots,    // [2][NW] u64, zeroed per call
    int*                __restrict__ idx,      // (MSAMP) out
    const float*        __restrict__ feat,
    const float*        __restrict__ Wq, const float* __restrict__ bq,
    unsigned short*     __restrict__ qb)       // (N, D) bf16 out (may be null)
{
    if (blockIdx.x < NW) {
        // ------------------------- FPS branch ----------------------------
        if (threadIdx.x >= 64) return;
        const int l = threadIdx.x;
        const int g = blockIdx.x;
        const int base = g * (FPT * 64) + l;

        float px[FPT], py[FPT], pz[FPT], dd[FPT];
#pragma unroll
        for (int i = 0; i < FPT; i++) {
            int p = base + i * 64;
            px[i] = xyz[3 * p + 0];
            py[i] = xyz[3 * p + 1];
            pz[i] = xyz[3 * p + 2];
            dd[i] = 1e10f;
        }
        if (g == 0 && l == 0) idx[0] = 0;

        float cx = xyz[0], cy = xyz[1], cz = xyz[2];   // centroid 0 = point 0

        for (int it = 1; it < MSAMP; ++it) {
            float vmax = -1.0f;
            int   imax = 0;
#pragma unroll
            for (int i = 0; i < FPT; i++) {
                float dx = __fsub_rn(px[i], cx);
                float dy = __fsub_rn(py[i], cy);
                float dz = __fsub_rn(pz[i], cz);
                float d  = __fadd_rn(__fadd_rn(__fmul_rn(dx, dx), __fmul_rn(dy, dy)),
                                     __fmul_rn(dz, dz));
                float nd = fminf(dd[i], d);
                dd[i] = nd;
                bool c = nd > vmax;              // strict >: keeps smallest idx
                vmax = c ? nd : vmax;
                imax = c ? (base + i * 64) : imax;
            }
            // pack: f32 bits high (non-neg -> monotone), tag mid, inv-idx low
            unsigned long long pack =
                (((unsigned long long)__float_as_uint(vmax)) << 32) |
                (((unsigned long long)(unsigned)it) << 16) |
                (unsigned long long)(0xFFFFu - (unsigned)imax);

            // in-wave butterfly (positive f64 patterns: fmax == u64 max)
            double dp = __longlong_as_double((long long)pack);
#pragma unroll
            for (int s = 1; s < 64; s <<= 1)
                dp = fmax(dp, __shfl_xor(dp, s, 64));
            unsigned long long wbest = (unsigned long long)__double_as_longlong(dp);

            // publish: ONE u64 per wave
            const int ph = it & 1;
            if (l == 0)
                __hip_atomic_store(slots + (ph * NW + g), wbest,
                                   __ATOMIC_RELAXED, __HIP_MEMORY_SCOPE_AGENT);

            // poll: one tagged u64 per lane
            const unsigned long long* Q = slots + ph * NW;
            unsigned long long u;
            for (;;) {
                u = __hip_atomic_load(Q + l, __ATOMIC_RELAXED,
                                      __HIP_MEMORY_SCOPE_AGENT);
                if (__all(((unsigned)(u >> 16) & 0xFFFFu) == (unsigned)it)) break;
            }

            // global winner butterfly
            double gp = __longlong_as_double((long long)u);
#pragma unroll
            for (int s = 1; s < 64; s <<= 1)
                gp = fmax(gp, __shfl_xor(gp, s, 64));
            unsigned long long gbest = (unsigned long long)__double_as_longlong(gp);
            int win = 0xFFFF - (int)(gbest & 0xFFFFu);

            // winner coords from read-only xyz (L2-resident, never stale)
            cx = xyz[3 * win + 0];
            cy = xyz[3 * win + 1];
            cz = xyz[3 * win + 2];

            if (g == 0 && l == 0) idx[it] = win;
        }
        return;
    }

    // --------------------- q-projection branch (shadow) -------------------
    if (qb == nullptr) return;
    const int tid  = threadIdx.x;
    const int ln   = tid & 63;
    const int wid  = tid >> 6;
    const int wr   = wid & 1;
    const int wc   = wid >> 1;
    const int r0   = (blockIdx.x - NW) * 128;
    const int lrow = ln & 15;
    const int lk   = (ln >> 4) * 8;
    const int crow = (ln >> 4) * 4;

    const f32x4_t fzero = {0.f, 0.f, 0.f, 0.f};
    f32x4_t qa[4][8];
#pragma unroll
    for (int m = 0; m < 4; m++)
#pragma unroll
        for (int n = 0; n < 8; n++) qa[m][n] = fzero;

#pragma unroll
    for (int kb = 0; kb < DMODEL; kb += 32) {
        bf16x8_t A[4], B[8];
#pragma unroll
        for (int m = 0; m < 4; m++)
            A[m] = cvt8(feat + (size_t)(r0 + wr * 64 + m * 16 + lrow) * DMODEL + kb + lk);
#pragma unroll
        for (int n = 0; n < 8; n++)
            B[n] = cvt8(Wq + (size_t)(wc * 128 + n * 16 + lrow) * DMODEL + kb + lk);
#pragma unroll
        for (int m = 0; m < 4; m++)
#pragma unroll
            for (int n = 0; n < 8; n++)
                qa[m][n] = __builtin_amdgcn_mfma_f32_16x16x32_bf16(
                    A[m], B[n], qa[m][n], 0, 0, 0);
    }
#pragma unroll
    for (int n = 0; n < 8; n++) {
        float bqv = bq[wc * 128 + n * 16 + lrow];
#pragma unroll
        for (int m = 0; m < 4; m++)
#pragma unroll
            for (int r = 0; r < 4; r++)
                qb[(size_t)(r0 + wr * 64 + m * 16 + crow + r) * DMODEL +
                   wc * 128 + n * 16 + lrow] = (unsigned short)f2bs(qa[m][n][r] + bqv);
    }
}

// ---------------------------------------------------------------------------
// Gather + K/V projection in f32; outputs bf16. k pre-scaled by 1/16 (exact),
// row-major (j,k); v stored transposed (d,j).
// ---------------------------------------------------------------------------
__global__ __launch_bounds__(256) void kv_kernel(
    const float* __restrict__ feat,
    const float* __restrict__ Wk, const float* __restrict__ bk,
    const float* __restrict__ Wv, const float* __restrict__ bv,
    const int* __restrict__ idx,
    unsigned short* __restrict__ k_s,   // (MSAMP, DMODEL) bf16, * 1/16
    unsigned short* __restrict__ vT)    // (DMODEL, MSAMP) bf16
{
    __shared__ float fl[4][DMODEL];
    const int t  = threadIdx.x;
    const int j0 = blockIdx.x * 4;
    {
        int jj = t >> 6;
        int e  = (t & 63) * 4;
        int src = idx[j0 + jj];
        f32x4_t v = *(const f32x4_t*)(feat + (size_t)src * DMODEL + e);
        fl[jj][e + 0] = v[0];
        fl[jj][e + 1] = v[1];
        fl[jj][e + 2] = v[2];
        fl[jj][e + 3] = v[3];
    }
    __syncthreads();

    float ak[4] = {0.f, 0.f, 0.f, 0.f};
    float av[4] = {0.f, 0.f, 0.f, 0.f};
    const float* wkr = Wk + (size_t)t * DMODEL;
    const float* wvr = Wv + (size_t)t * DMODEL;
#pragma unroll 4
    for (int in = 0; in < DMODEL; in += 4) {
        f32x4_t ku = *(const f32x4_t*)(wkr + in);
        f32x4_t vu = *(const f32x4_t*)(wvr + in);
#pragma unroll
        for (int jj = 0; jj < 4; jj++) {
            ak[jj] = fmaf(fl[jj][in + 0], ku[0], ak[jj]);
            ak[jj] = fmaf(fl[jj][in + 1], ku[1], ak[jj]);
            ak[jj] = fmaf(fl[jj][in + 2], ku[2], ak[jj]);
            ak[jj] = fmaf(fl[jj][in + 3], ku[3], ak[jj]);
            av[jj] = fmaf(fl[jj][in + 0], vu[0], av[jj]);
            av[jj] = fmaf(fl[jj][in + 1], vu[1], av[jj]);
            av[jj] = fmaf(fl[jj][in + 2], vu[2], av[jj]);
            av[jj] = fmaf(fl[jj][in + 3], vu[3], av[jj]);
        }
    }
    float bkv = bk[t];
    float bvv = bv[t];
#pragma unroll
    for (int jj = 0; jj < 4; jj++) {
        k_s[(unsigned)(j0 + jj) * DMODEL + t] = (unsigned short)f2bs((ak[jj] + bkv) * 0.0625f);
        vT[(unsigned)t * MSAMP + (j0 + jj)]   = (unsigned short)f2bs(av[jj] + bvv);
    }
}

// ---------------------------------------------------------------------------
// w -> res -> concat. 128-row tile per WG, 4 waves (2 row x 2 col), MFMA
// 16x16x32 bf16. q comes from qb (hoisted) or is computed inline (fallback).
// ---------------------------------------------------------------------------
#define QS  264   // qlds row stride (bf16), pad kills 512B-stride conflicts
#define WSR 136   // wlds row stride (bf16)
#define RS  258   // rlds row stride (f32)
#define MAIN_LDS (128 * RS * 4)   // 132096 B

__global__ __launch_bounds__(256, 1) void main_kernel(
    const float* __restrict__ feat,
    const float* __restrict__ Wq, const float* __restrict__ bq,
    const unsigned short* __restrict__ qb,   // null if not hoisted
    const unsigned short* __restrict__ k_s,
    const unsigned short* __restrict__ vT,
    float* __restrict__ out,
    int hoisted)
{
    extern __shared__ char smem[];
    unsigned short* qlds = (unsigned short*)smem;
    unsigned short* wlds = (unsigned short*)(smem + 128 * QS * 2);

    const int tid  = threadIdx.x;
    const int ln   = tid & 63;
    const int wid  = tid >> 6;
    const int wr   = wid & 1;
    const int wc   = wid >> 1;
    const int r0   = blockIdx.x * 128;
    const int lrow = ln & 15;
    const int lk   = (ln >> 4) * 8;
    const int crow = (ln >> 4) * 4;

    const f32x4_t fzero = {0.f, 0.f, 0.f, 0.f};

    // ---- phase 1: q tile into qlds ----
    if (hoisted) {
#pragma unroll
        for (int c = tid; c < 128 * 32; c += 256) {
            int row = c >> 5, col = (c & 31) * 8;
            *(bf16x8_t*)(qlds + row * QS + col) =
                *(const bf16x8_t*)(qb + (size_t)(r0 + row) * DMODEL + col);
        }
    } else {
        f32x4_t qa[4][8];
#pragma unroll
        for (int m = 0; m < 4; m++)
#pragma unroll
            for (int n = 0; n < 8; n++) qa[m][n] = fzero;
#pragma unroll
        for (int kb = 0; kb < DMODEL; kb += 32) {
            bf16x8_t A[4], B[8];
#pragma unroll
            for (int m = 0; m < 4; m++)
                A[m] = cvt8(feat + (size_t)(r0 + wr * 64 + m * 16 + lrow) * DMODEL + kb + lk);
#pragma unroll
            for (int n = 0; n < 8; n++)
                B[n] = cvt8(Wq + (size_t)(wc * 128 + n * 16 + lrow) * DMODEL + kb + lk);
#pragma unroll
            for (int m = 0; m < 4; m++)
#pragma unroll
                for (int n = 0; n < 8; n++)
                    qa[m][n] = __builtin_amdgcn_mfma_f32_16x16x32_bf16(
                        A[m], B[n], qa[m][n], 0, 0, 0);
        }
#pragma unroll
        for (int n = 0; n < 8; n++) {
            float bqv = bq[wc * 128 + n * 16 + lrow];
#pragma unroll
            for (int m = 0; m < 4; m++)
#pragma unroll
                for (int r = 0; r < 4; r++)
                    qlds[(wr * 64 + m * 16 + crow + r) * QS + wc * 128 + n * 16 + lrow] =
                        (unsigned short)f2bs(qa[m][n][r] + bqv);
        }
    }
    __syncthreads();

    // ---- phase 2: flash-style w-chunk -> res accumulation ----
    f32x4_t racc[4][8];
#pragma unroll
    for (int m = 0; m < 4; m++)
#pragma unroll
        for (int n = 0; n < 8; n++) racc[m][n] = fzero;

    for (int jb = 0; jb < 8; jb++) {
        f32x4_t wa[4][4];
#pragma unroll
        for (int m = 0; m < 4; m++)
#pragma unroll
            for (int n = 0; n < 4; n++) wa[m][n] = fzero;

#pragma unroll
        for (int kb = 0; kb < DMODEL; kb += 32) {
            bf16x8_t A[4], B[4];
#pragma unroll
            for (int m = 0; m < 4; m++)
                A[m] = *(const bf16x8_t*)(qlds + (wr * 64 + m * 16 + lrow) * QS + kb + lk);
#pragma unroll
            for (int n = 0; n < 4; n++)
                B[n] = *(const bf16x8_t*)(k_s +
                    (size_t)(jb * 128 + wc * 64 + n * 16 + lrow) * DMODEL + kb + lk);
#pragma unroll
            for (int m = 0; m < 4; m++)
#pragma unroll
                for (int n = 0; n < 4; n++)
                    wa[m][n] = __builtin_amdgcn_mfma_f32_16x16x32_bf16(
                        A[m], B[n], wa[m][n], 0, 0, 0);
        }
#pragma unroll
        for (int m = 0; m < 4; m++)
#pragma unroll
            for (int n = 0; n < 4; n++)
#pragma unroll
                for (int r = 0; r < 4; r++)
                    wlds[(wr * 64 + m * 16 + crow + r) * WSR + wc * 64 + n * 16 + lrow] =
                        (unsigned short)f2bs(wa[m][n][r]);
        __syncthreads();

#pragma unroll
        for (int kb2 = 0; kb2 < 128; kb2 += 32) {
            bf16x8_t A[4], B[8];
#pragma unroll
            for (int m = 0; m < 4; m++)
                A[m] = *(const bf16x8_t*)(wlds + (wr * 64 + m * 16 + lrow) * WSR + kb2 + lk);
#pragma unroll
            for (int n = 0; n < 8; n++)
                B[n] = *(const bf16x8_t*)(vT +
                    (size_t)(wc * 128 + n * 16 + lrow) * MSAMP + jb * 128 + kb2 + lk);
#pragma unroll
            for (int m = 0; m < 4; m++)
#pragma unroll
                for (int n = 0; n < 8; n++)
                    racc[m][n] = __builtin_amdgcn_mfma_f32_16x16x32_bf16(
                        A[m], B[n], racc[m][n], 0, 0, 0);
        }
        __syncthreads();
    }

    // ---- phase 3: epilogue, f32 res -> LDS, coalesced f32 [res|feat] store ----
    float* rlds = (float*)smem;
#pragma unroll
    for (int m = 0; m < 4; m++)
#pragma unroll
        for (int n = 0; n < 8; n++)
#pragma unroll
            for (int r = 0; r < 4; r++)
                rlds[(wr * 64 + m * 16 + crow + r) * RS + wc * 128 + n * 16 + lrow] =
                    racc[m][n][r];
    __syncthreads();

#pragma unroll
    for (int base = 0; base < 128; base += 4) {
        int row = base + wid;
        f32x4_t a = *(const f32x4_t*)(rlds + row * RS + ln * 4);
        f32x4_t b = *(const f32x4_t*)(feat + (size_t)(r0 + row) * DMODEL + ln * 4);
        *(f32x4_t*)(out + (size_t)(r0 + row) * 512 + ln * 4)       = a;
        *(f32x4_t*)(out + (size_t)(r0 + row) * 512 + 256 + ln * 4) = b;
    }
}

// ---------------------------------------------------------------------------
extern "C" void kernel_launch(void* const* d_in, const int* in_sizes, int n_in,
                              void* d_out, int out_size, void* d_ws, size_t ws_size,
                              hipStream_t stream) {
    const float* p_xyz = (const float*)d_in[0];
    const float* feat  = (const float*)d_in[1];
    const float* Wq    = (const float*)d_in[2];
    const float* bq    = (const float*)d_in[3];
    const float* Wk    = (const float*)d_in[4];
    const float* bk    = (const float*)d_in[5];
    const float* Wv    = (const float*)d_in[6];
    const float* bv    = (const float*)d_in[7];
    float* out = (float*)d_out;

    char* ws = (char*)d_ws;
    unsigned long long* slots = (unsigned long long*)ws;                //   1 KB [2][NW]
    int*                idx   = (int*)(ws + 8192);                      //   4 KB
    unsigned short*     k_s   = (unsigned short*)(ws + 16384);          // 512 KB
    unsigned short*     vT    = (unsigned short*)(ws + 16384 + 524288); // 512 KB
    size_t qb_off = 16384 + 2 * 524288;
    size_t req    = qb_off + (size_t)N_PTS * DMODEL * 2;                // + 33.5 MB
    int hoist = (ws_size >= req) ? 1 : 0;
    unsigned short* qb = hoist ? (unsigned short*)(ws + qb_off) : nullptr;

    hipMemsetAsync(d_ws, 0, 4096, stream);   // invalidate slots every call

    int fgrid = NW + (hoist ? (N_PTS / 128) : 0);
    hipLaunchKernelGGL(fps_q_kernel, dim3(fgrid), dim3(256), 0, stream,
                       p_xyz, slots, idx, feat, Wq, bq, qb);
    hipLaunchKernelGGL(kv_kernel, dim3(MSAMP / 4), dim3(256), 0, stream,
                       feat, Wk, bk, Wv, bv, idx, k_s, vT);
    hipFuncSetAttribute((const void*)main_kernel,
                        hipFuncAttributeMaxDynamicSharedMemorySize, MAIN_LDS);
    hipLaunchKernelGGL(main_kernel, dim3(N_PTS / 128), dim3(256), MAIN_LDS, stream,
                       feat, Wq, bq, qb, k_s, vT, out, hoist);
}

// Round 5
// 2287.043 us; speedup vs baseline: 1.4644x; 1.4644x over previous
//
#include <hip/hip_runtime.h>
#include <hip/hip_bf16.h>

#define N_PTS  65536
#define DMODEL 256
#define MSAMP  1024

#define NW  64   // FPS waves = single-wave workgroups (all co-resident)
#define FPT 16   // points per lane: 65536 / (64 * 64)
#define SLW 16   // u64s per slot line: 128B stride -> one wave per cache line

typedef short bf16x8_t __attribute__((ext_vector_type(8)));
typedef float f32x4_t  __attribute__((ext_vector_type(4)));

__device__ __forceinline__ short f2bs(float f) {
    __hip_bfloat16 h = __float2bfloat16(f);   // RNE
    return *reinterpret_cast<short*>(&h);
}

// load 8 consecutive f32 and convert to a bf16x8 MFMA fragment
__device__ __forceinline__ bf16x8_t cvt8(const float* p) {
    f32x4_t a = *(const f32x4_t*)(p);
    f32x4_t b = *(const f32x4_t*)(p + 4);
    bf16x8_t r;
#pragma unroll
    for (int i = 0; i < 4; i++) {
        r[i]     = f2bs(a[i]);
        r[i + 4] = f2bs(b[i]);
    }
    return r;
}

// ---------------------------------------------------------------------------
// FPS: 64 single-wave blocks. Per iteration: in-register min-update + argmax,
// 6-step shfl butterfly (u64 packs compared as positive f64 bit patterns),
// publish pack + winning coords (4 tagged u64s = 32B) into the wave's OWN
// 128B slot line (no line sharing -> no store ping-pong at the coherence
// point), poll: lane l reads wave l's 4 u64s (lines written once/iter,
// read-shared), butterfly the packs, winner coords arrive via shfl from the
// slot data. No atomicRMW, no LDS, no __syncthreads, no dependent xyz load.
// Slots double-buffered by iteration parity (2-phase safe: a wave cannot
// re-enter the same parity before every wave has passed the previous poll).
// Exact numpy arithmetic: per-op RN f32, ((dx^2+dy^2)+dz^2), first-index
// argmax tie-break via (value, 0xFFFF-idx) packing.
// ---------------------------------------------------------------------------
__global__ __launch_bounds__(64) void fps_kernel(
    const float*        __restrict__ xyz,      // (N,3) f32
    unsigned long long* __restrict__ slots,    // [2][NW][SLW] u64, zeroed per call
    int*                __restrict__ idx)      // (MSAMP) out
{
    const int l = threadIdx.x;       // 0..63
    const int g = blockIdx.x;        // 0..63
    const int base = g * (FPT * 64) + l;

    float px[FPT], py[FPT], pz[FPT], dd[FPT];
#pragma unroll
    for (int i = 0; i < FPT; i++) {
        int p = base + i * 64;
        px[i] = xyz[3 * p + 0];
        py[i] = xyz[3 * p + 1];
        pz[i] = xyz[3 * p + 2];
        dd[i] = 1e10f;
    }
    if (g == 0 && l == 0) idx[0] = 0;

    float cx = xyz[0], cy = xyz[1], cz = xyz[2];   // centroid 0 = point 0

    for (int it = 1; it < MSAMP; ++it) {
        // ---- local min-update + argmax (tracks winning coords in-register) --
        float vmax = -1.0f, bx = 0.f, by = 0.f, bz = 0.f;
        int   imax = 0;
#pragma unroll
        for (int i = 0; i < FPT; i++) {
            float dx = __fsub_rn(px[i], cx);
            float dy = __fsub_rn(py[i], cy);
            float dz = __fsub_rn(pz[i], cz);
            float d  = __fadd_rn(__fadd_rn(__fmul_rn(dx, dx), __fmul_rn(dy, dy)),
                                 __fmul_rn(dz, dz));
            float nd = fminf(dd[i], d);
            dd[i] = nd;
            bool c = nd > vmax;                 // strict >: keeps smallest idx
            vmax = c ? nd    : vmax;
            imax = c ? (base + i * 64) : imax;
            bx   = c ? px[i] : bx;
            by   = c ? py[i] : by;
            bz   = c ? pz[i] : bz;
        }
        // pack: f32 bits high (non-neg -> monotone), tag mid, inv-idx low
        unsigned long long pack =
            (((unsigned long long)__float_as_uint(vmax)) << 32) |
            (((unsigned long long)(unsigned)it) << 16) |
            (unsigned long long)(0xFFFFu - (unsigned)imax);

        // ---- in-wave butterfly (positive f64 bit patterns: fmax == u64 max)
        double dp = __longlong_as_double((long long)pack);
#pragma unroll
        for (int s = 1; s < 64; s <<= 1)
            dp = fmax(dp, __shfl_xor(dp, s, 64));
        unsigned long long wbest = (unsigned long long)__double_as_longlong(dp);

        // owner lane -> wave-candidate coords to all lanes
        unsigned long long mo = __ballot(pack == wbest);
        int ol = __ffsll((unsigned long long)mo) - 1;
        float wx = __shfl(bx, ol, 64);
        float wy = __shfl(by, ol, 64);
        float wz = __shfl(bz, ol, 64);

        // ---- publish: lanes 0-3 store 4 tagged u64s (32B) into OWN line ----
        const int ph = it & 1;
        unsigned long long sv = wbest;
        unsigned long long xp = (((unsigned long long)__float_as_uint(wx)) << 32) | (unsigned)it;
        unsigned long long yp = (((unsigned long long)__float_as_uint(wy)) << 32) | (unsigned)it;
        unsigned long long zp = (((unsigned long long)__float_as_uint(wz)) << 32) | (unsigned)it;
        sv = (l == 1) ? xp : sv;
        sv = (l == 2) ? yp : sv;
        sv = (l == 3) ? zp : sv;
        if (l < 4)
            __hip_atomic_store(slots + ((size_t)(ph * NW + g) * SLW + l), sv,
                               __ATOMIC_RELAXED, __HIP_MEMORY_SCOPE_AGENT);

        // ---- poll: lane l reads wave l's 4 u64s, tag-validated -------------
        const unsigned long long* Q = slots + (size_t)ph * NW * SLW + (size_t)l * SLW;
        unsigned long long u0, u1, u2, u3;
        for (;;) {
            u0 = __hip_atomic_load(Q + 0, __ATOMIC_RELAXED, __HIP_MEMORY_SCOPE_AGENT);
            u1 = __hip_atomic_load(Q + 1, __ATOMIC_RELAXED, __HIP_MEMORY_SCOPE_AGENT);
            u2 = __hip_atomic_load(Q + 2, __ATOMIC_RELAXED, __HIP_MEMORY_SCOPE_AGENT);
            u3 = __hip_atomic_load(Q + 3, __ATOMIC_RELAXED, __HIP_MEMORY_SCOPE_AGENT);
            bool ok = (((unsigned)(u0 >> 16) & 0xFFFFu) == (unsigned)it) &
                      ((unsigned)u1 == (unsigned)it) &
                      ((unsigned)u2 == (unsigned)it) &
                      ((unsigned)u3 == (unsigned)it);
            if (__all(ok)) break;
        }

        // ---- global winner butterfly + coords via shfl --------------------
        double gp = __longlong_as_double((long long)u0);
#pragma unroll
        for (int s = 1; s < 64; s <<= 1)
            gp = fmax(gp, __shfl_xor(gp, s, 64));
        unsigned long long gbest = (unsigned long long)__double_as_longlong(gp);
        int win = 0xFFFF - (int)(gbest & 0xFFFFu);

        unsigned long long mw = __ballot(u0 == gbest);
        int wl = __ffsll((unsigned long long)mw) - 1;
        cx = __shfl(__uint_as_float((unsigned)(u1 >> 32)), wl, 64);
        cy = __shfl(__uint_as_float((unsigned)(u2 >> 32)), wl, 64);
        cz = __shfl(__uint_as_float((unsigned)(u3 >> 32)), wl, 64);

        if (g == 0 && l == 0) idx[it] = win;
    }
}

// ---------------------------------------------------------------------------
// Gather + K/V projection in f32; outputs bf16. k pre-scaled by 1/16 (exact),
// row-major (j,k); v stored transposed (d,j).
// ---------------------------------------------------------------------------
__global__ __launch_bounds__(256) void kv_kernel(
    const float* __restrict__ feat,
    const float* __restrict__ Wk, const float* __restrict__ bk,
    const float* __restrict__ Wv, const float* __restrict__ bv,
    const int* __restrict__ idx,
    unsigned short* __restrict__ k_s,   // (MSAMP, DMODEL) bf16, * 1/16
    unsigned short* __restrict__ vT)    // (DMODEL, MSAMP) bf16
{
    __shared__ float fl[4][DMODEL];
    const int t  = threadIdx.x;
    const int j0 = blockIdx.x * 4;
    {
        int jj = t >> 6;
        int e  = (t & 63) * 4;
        int src = idx[j0 + jj];
        f32x4_t v = *(const f32x4_t*)(feat + (size_t)src * DMODEL + e);
        fl[jj][e + 0] = v[0];
        fl[jj][e + 1] = v[1];
        fl[jj][e + 2] = v[2];
        fl[jj][e + 3] = v[3];
    }
    __syncthreads();

    float ak[4] = {0.f, 0.f, 0.f, 0.f};
    float av[4] = {0.f, 0.f, 0.f, 0.f};
    const float* wkr = Wk + (size_t)t * DMODEL;
    const float* wvr = Wv + (size_t)t * DMODEL;
#pragma unroll 4
    for (int in = 0; in < DMODEL; in += 4) {
        f32x4_t ku = *(const f32x4_t*)(wkr + in);
        f32x4_t vu = *(const f32x4_t*)(wvr + in);
#pragma unroll
        for (int jj = 0; jj < 4; jj++) {
            ak[jj] = fmaf(fl[jj][in + 0], ku[0], ak[jj]);
            ak[jj] = fmaf(fl[jj][in + 1], ku[1], ak[jj]);
            ak[jj] = fmaf(fl[jj][in + 2], ku[2], ak[jj]);
            ak[jj] = fmaf(fl[jj][in + 3], ku[3], ak[jj]);
            av[jj] = fmaf(fl[jj][in + 0], vu[0], av[jj]);
            av[jj] = fmaf(fl[jj][in + 1], vu[1], av[jj]);
            av[jj] = fmaf(fl[jj][in + 2], vu[2], av[jj]);
            av[jj] = fmaf(fl[jj][in + 3], vu[3], av[jj]);
        }
    }
    float bkv = bk[t];
    float bvv = bv[t];
#pragma unroll
    for (int jj = 0; jj < 4; jj++) {
        k_s[(unsigned)(j0 + jj) * DMODEL + t] = (unsigned short)f2bs((ak[jj] + bkv) * 0.0625f);
        vT[(unsigned)t * MSAMP + (j0 + jj)]   = (unsigned short)f2bs(av[jj] + bvv);
    }
}

// ---------------------------------------------------------------------------
// Fused q -> w -> res -> concat. 128-row tile per WG, 4 waves (2 row x 2 col),
// MFMA 16x16x32 bf16 (f32 inputs converted inline). Epilogue stages f32 res
// in LDS and writes coalesced f32 [res | features].
// ---------------------------------------------------------------------------
#define QS  264   // qlds row stride (bf16), pad kills 512B-stride conflicts
#define WSR 136   // wlds row stride (bf16)
#define RS  258   // rlds row stride (f32)
#define MAIN_LDS (128 * RS * 4)   // 132096 B

__global__ __launch_bounds__(256, 1) void main_kernel(
    const float* __restrict__ feat,
    const float* __restrict__ Wq, const float* __restrict__ bq,
    const unsigned short* __restrict__ k_s,
    const unsigned short* __restrict__ vT,
    float* __restrict__ out)
{
    extern __shared__ char smem[];
    unsigned short* qlds = (unsigned short*)smem;
    unsigned short* wlds = (unsigned short*)(smem + 128 * QS * 2);

    const int tid  = threadIdx.x;
    const int ln   = tid & 63;
    const int wid  = tid >> 6;
    const int wr   = wid & 1;
    const int wc   = wid >> 1;
    const int r0   = blockIdx.x * 128;
    const int lrow = ln & 15;
    const int lk   = (ln >> 4) * 8;
    const int crow = (ln >> 4) * 4;

    const f32x4_t fzero = {0.f, 0.f, 0.f, 0.f};

    // ---- phase 1: q = feat @ Wq^T + bq -> bf16 in qlds ----
    f32x4_t qa[4][8];
#pragma unroll
    for (int m = 0; m < 4; m++)
#pragma unroll
        for (int n = 0; n < 8; n++) qa[m][n] = fzero;

#pragma unroll
    for (int kb = 0; kb < DMODEL; kb += 32) {
        bf16x8_t A[4], B[8];
#pragma unroll
        for (int m = 0; m < 4; m++)
            A[m] = cvt8(feat + (size_t)(r0 + wr * 64 + m * 16 + lrow) * DMODEL + kb + lk);
#pragma unroll
        for (int n = 0; n < 8; n++)
            B[n] = cvt8(Wq + (size_t)(wc * 128 + n * 16 + lrow) * DMODEL + kb + lk);
#pragma unroll
        for (int m = 0; m < 4; m++)
#pragma unroll
            for (int n = 0; n < 8; n++)
                qa[m][n] = __builtin_amdgcn_mfma_f32_16x16x32_bf16(
                    A[m], B[n], qa[m][n], 0, 0, 0);
    }
#pragma unroll
    for (int n = 0; n < 8; n++) {
        float bqv = bq[wc * 128 + n * 16 + lrow];
#pragma unroll
        for (int m = 0; m < 4; m++)
#pragma unroll
            for (int r = 0; r < 4; r++)
                qlds[(wr * 64 + m * 16 + crow + r) * QS + wc * 128 + n * 16 + lrow] =
                    (unsigned short)f2bs(qa[m][n][r] + bqv);
    }
    __syncthreads();

    // ---- phase 2: flash-style w-chunk -> res accumulation ----
    f32x4_t racc[4][8];
#pragma unroll
    for (int m = 0; m < 4; m++)
#pragma unroll
        for (int n = 0; n < 8; n++) racc[m][n] = fzero;

    for (int jb = 0; jb < 8; jb++) {
        f32x4_t wa[4][4];
#pragma unroll
        for (int m = 0; m < 4; m++)
#pragma unroll
            for (int n = 0; n < 4; n++) wa[m][n] = fzero;

#pragma unroll
        for (int kb = 0; kb < DMODEL; kb += 32) {
            bf16x8_t A[4], B[4];
#pragma unroll
            for (int m = 0; m < 4; m++)
                A[m] = *(const bf16x8_t*)(qlds + (wr * 64 + m * 16 + lrow) * QS + kb + lk);
#pragma unroll
            for (int n = 0; n < 4; n++)
                B[n] = *(const bf16x8_t*)(k_s +
                    (size_t)(jb * 128 + wc * 64 + n * 16 + lrow) * DMODEL + kb + lk);
#pragma unroll
            for (int m = 0; m < 4; m++)
#pragma unroll
                for (int n = 0; n < 4; n++)
                    wa[m][n] = __builtin_amdgcn_mfma_f32_16x16x32_bf16(
                        A[m], B[n], wa[m][n], 0, 0, 0);
        }
#pragma unroll
        for (int m = 0; m < 4; m++)
#pragma unroll
            for (int n = 0; n < 4; n++)
#pragma unroll
                for (int r = 0; r < 4; r++)
                    wlds[(wr * 64 + m * 16 + crow + r) * WSR + wc * 64 + n * 16 + lrow] =
                        (unsigned short)f2bs(wa[m][n][r]);
        __syncthreads();

#pragma unroll
        for (int kb2 = 0; kb2 < 128; kb2 += 32) {
            bf16x8_t A[4], B[8];
#pragma unroll
            for (int m = 0; m < 4; m++)
                A[m] = *(const bf16x8_t*)(wlds + (wr * 64 + m * 16 + lrow) * WSR + kb2 + lk);
#pragma unroll
            for (int n = 0; n < 8; n++)
                B[n] = *(const bf16x8_t*)(vT +
                    (size_t)(wc * 128 + n * 16 + lrow) * MSAMP + jb * 128 + kb2 + lk);
#pragma unroll
            for (int m = 0; m < 4; m++)
#pragma unroll
                for (int n = 0; n < 8; n++)
                    racc[m][n] = __builtin_amdgcn_mfma_f32_16x16x32_bf16(
                        A[m], B[n], racc[m][n], 0, 0, 0);
        }
        __syncthreads();
    }

    // ---- phase 3: epilogue, f32 res -> LDS, coalesced f32 [res|feat] store ----
    float* rlds = (float*)smem;   // qlds/wlds dead now
#pragma unroll
    for (int m = 0; m < 4; m++)
#pragma unroll
        for (int n = 0; n < 8; n++)
#pragma unroll
            for (int r = 0; r < 4; r++)
                rlds[(wr * 64 + m * 16 + crow + r) * RS + wc * 128 + n * 16 + lrow] =
                    racc[m][n][r];
    __syncthreads();

#pragma unroll
    for (int base = 0; base < 128; base += 4) {
        int row = base + wid;
        f32x4_t a = *(const f32x4_t*)(rlds + row * RS + ln * 4);
        f32x4_t b = *(const f32x4_t*)(feat + (size_t)(r0 + row) * DMODEL + ln * 4);
        *(f32x4_t*)(out + (size_t)(r0 + row) * 512 + ln * 4)       = a;
        *(f32x4_t*)(out + (size_t)(r0 + row) * 512 + 256 + ln * 4) = b;
    }
}

// ---------------------------------------------------------------------------
extern "C" void kernel_launch(void* const* d_in, const int* in_sizes, int n_in,
                              void* d_out, int out_size, void* d_ws, size_t ws_size,
                              hipStream_t stream) {
    const float* p_xyz = (const float*)d_in[0];
    const float* feat  = (const float*)d_in[1];
    const float* Wq    = (const float*)d_in[2];
    const float* bq    = (const float*)d_in[3];
    const float* Wk    = (const float*)d_in[4];
    const float* bk    = (const float*)d_in[5];
    const float* Wv    = (const float*)d_in[6];
    const float* bv    = (const float*)d_in[7];
    float* out = (float*)d_out;

    char* ws = (char*)d_ws;
    unsigned long long* slots = (unsigned long long*)ws;                //  16 KB [2][NW][SLW]
    int*                idx   = (int*)(ws + 16384);                     //   4 KB
    unsigned short*     k_s   = (unsigned short*)(ws + 32768);          // 512 KB
    unsigned short*     vT    = (unsigned short*)(ws + 32768 + 524288); // 512 KB

    hipMemsetAsync(d_ws, 0, 16384, stream);   // invalidate slots every call

    hipLaunchKernelGGL(fps_kernel, dim3(NW), dim3(64), 0, stream,
                       p_xyz, slots, idx);
    hipLaunchKernelGGL(kv_kernel, dim3(MSAMP / 4), dim3(256), 0, stream,
                       feat, Wk, bk, Wv, bv, idx, k_s, vT);
    hipFuncSetAttribute((const void*)main_kernel,
                        hipFuncAttributeMaxDynamicSharedMemorySize, MAIN_LDS);
    hipLaunchKernelGGL(main_kernel, dim3(N_PTS / 128), dim3(256), MAIN_LDS, stream,
                       feat, Wq, bq, k_s, vT, out);
}

// Round 8
// 2212.583 us; speedup vs baseline: 1.5136x; 1.0337x over previous
//
#include <hip/hip_runtime.h>
#include <hip/hip_bf16.h>

#define N_PTS  65536
#define DMODEL 256
#define MSAMP  1024

#define NW  64   // FPS waves = single-wave workgroups (all co-resident)
#define FPT 16   // points per lane: 65536 / (64 * 64)
#define SLW 16   // u64s per slot line: 128B stride, one wave per line

typedef short bf16x8_t __attribute__((ext_vector_type(8)));
typedef float f32x4_t  __attribute__((ext_vector_type(4)));

__device__ __forceinline__ short f2bs(float f) {
    __hip_bfloat16 h = __float2bfloat16(f);   // RNE
    return *reinterpret_cast<short*>(&h);
}

// load 8 consecutive f32 and convert to a bf16x8 MFMA fragment
__device__ __forceinline__ bf16x8_t cvt8(const float* p) {
    f32x4_t a = *(const f32x4_t*)(p);
    f32x4_t b = *(const f32x4_t*)(p + 4);
    bf16x8_t r;
#pragma unroll
    for (int i = 0; i < 4; i++) { r[i] = f2bs(a[i]); r[i + 4] = f2bs(b[i]); }
    return r;
}

// ---------------------------------------------------------------------------
// FPS: 64 single-wave blocks (R5-proven liveness/protocol). R8 change vs R5:
// coherence-point traffic cut ~16x. Publish = ONE tagged u64 per wave into
// its own private 128B line; poll = one u64 per lane with s_sleep(2) between
// retries (first probe immediate); winner coords re-read from read-only
// xyz[3*win] (same-address broadcast, L2-resident, never stale). Double-
// buffered by iteration parity. Exact numpy arithmetic (per-op RN f32,
// ((dx^2+dy^2)+dz^2)) and first-index tie-break via (value, 0xFFFF-idx).
// ---------------------------------------------------------------------------
__global__ __launch_bounds__(64) void fps_kernel(
    const float*        __restrict__ xyz,      // (N,3) f32
    unsigned long long* __restrict__ slots,    // [2][NW][SLW] u64, zeroed per call
    int*                __restrict__ idx)      // (MSAMP) out
{
    const int l = threadIdx.x;       // 0..63
    const int g = blockIdx.x;        // 0..63
    const int base = g * (FPT * 64) + l;

    float px[FPT], py[FPT], pz[FPT], dd[FPT];
#pragma unroll
    for (int i = 0; i < FPT; i++) {
        int p = base + i * 64;
        px[i] = xyz[3 * p + 0];
        py[i] = xyz[3 * p + 1];
        pz[i] = xyz[3 * p + 2];
        dd[i] = 1e10f;
    }
    if (g == 0 && l == 0) idx[0] = 0;

    float cx = xyz[0], cy = xyz[1], cz = xyz[2];   // centroid 0 = point 0

    for (int it = 1; it < MSAMP; ++it) {
        // ---- local min-update + argmax --------------------------------
        float vmax = -1.0f;
        int   imax = 0;
#pragma unroll
        for (int i = 0; i < FPT; i++) {
            float dx = __fsub_rn(px[i], cx);
            float dy = __fsub_rn(py[i], cy);
            float dz = __fsub_rn(pz[i], cz);
            float d  = __fadd_rn(__fadd_rn(__fmul_rn(dx, dx), __fmul_rn(dy, dy)),
                                 __fmul_rn(dz, dz));
            float nd = fminf(dd[i], d);
            dd[i] = nd;
            bool c = nd > vmax;                 // strict >: keeps smallest idx
            vmax = c ? nd : vmax;
            imax = c ? (base + i * 64) : imax;
        }
        // pack: f32 bits high (non-neg -> monotone), tag mid, inv-idx low
        unsigned long long pack =
            (((unsigned long long)__float_as_uint(vmax)) << 32) |
            (((unsigned long long)(unsigned)it) << 16) |
            (unsigned long long)(0xFFFFu - (unsigned)imax);

        // ---- in-wave butterfly (positive f64 patterns: fmax == u64 max) ----
        double dp = __longlong_as_double((long long)pack);
#pragma unroll
        for (int s = 1; s < 64; s <<= 1)
            dp = fmax(dp, __shfl_xor(dp, s, 64));
        unsigned long long wbest = (unsigned long long)__double_as_longlong(dp);

        // ---- publish: ONE tagged u64 into the wave's private 128B line ----
        const int ph = it & 1;
        if (l == 0)
            __hip_atomic_store(slots + ((size_t)(ph * NW + g) * SLW), wbest,
                               __ATOMIC_RELAXED, __HIP_MEMORY_SCOPE_AGENT);

        // ---- poll: lane l reads wave l's u64; sleep-throttled retries -----
        const unsigned long long* Q = slots + (size_t)ph * NW * SLW + (size_t)l * SLW;
        unsigned long long u;
        for (;;) {
            u = __hip_atomic_load(Q, __ATOMIC_RELAXED, __HIP_MEMORY_SCOPE_AGENT);
            if (__all(((unsigned)(u >> 16) & 0xFFFFu) == (unsigned)it)) break;
            __builtin_amdgcn_s_sleep(2);       // ~128cy backoff: cut L3 churn
        }

        // ---- global winner butterfly --------------------------------------
        double gp = __longlong_as_double((long long)u);
#pragma unroll
        for (int s = 1; s < 64; s <<= 1)
            gp = fmax(gp, __shfl_xor(gp, s, 64));
        unsigned long long gbest = (unsigned long long)__double_as_longlong(gp);
        int win = 0xFFFF - (int)(gbest & 0xFFFFu);

        // ---- winner coords: same-address broadcast load (read-only data) --
        cx = xyz[3 * win + 0];
        cy = xyz[3 * win + 1];
        cz = xyz[3 * win + 2];

        if (g == 0 && l == 0) idx[it] = win;
    }
}

// ---------------------------------------------------------------------------
// Gather + K/V projection in f32; outputs bf16. k pre-scaled by 1/16 (exact),
// row-major (j,k); v stored transposed (d,j).   [unchanged from R5]
// ---------------------------------------------------------------------------
__global__ __launch_bounds__(256) void kv_kernel(
    const float* __restrict__ feat,
    const float* __restrict__ Wk, const float* __restrict__ bk,
    const float* __restrict__ Wv, const float* __restrict__ bv,
    const int* __restrict__ idx,
    unsigned short* __restrict__ k_s,   // (MSAMP, DMODEL) bf16, * 1/16
    unsigned short* __restrict__ vT)    // (DMODEL, MSAMP) bf16
{
    __shared__ float fl[4][DMODEL];
    const int t  = threadIdx.x;
    const int j0 = blockIdx.x * 4;
    {
        int jj = t >> 6;
        int e  = (t & 63) * 4;
        int src = idx[j0 + jj];
        f32x4_t v = *(const f32x4_t*)(feat + (size_t)src * DMODEL + e);
        fl[jj][e + 0] = v[0];
        fl[jj][e + 1] = v[1];
        fl[jj][e + 2] = v[2];
        fl[jj][e + 3] = v[3];
    }
    __syncthreads();

    float ak[4] = {0.f, 0.f, 0.f, 0.f};
    float av[4] = {0.f, 0.f, 0.f, 0.f};
    const float* wkr = Wk + (size_t)t * DMODEL;
    const float* wvr = Wv + (size_t)t * DMODEL;
#pragma unroll 4
    for (int in = 0; in < DMODEL; in += 4) {
        f32x4_t ku = *(const f32x4_t*)(wkr + in);
        f32x4_t vu = *(const f32x4_t*)(wvr + in);
#pragma unroll
        for (int jj = 0; jj < 4; jj++) {
            ak[jj] = fmaf(fl[jj][in + 0], ku[0], ak[jj]);
            ak[jj] = fmaf(fl[jj][in + 1], ku[1], ak[jj]);
            ak[jj] = fmaf(fl[jj][in + 2], ku[2], ak[jj]);
            ak[jj] = fmaf(fl[jj][in + 3], ku[3], ak[jj]);
            av[jj] = fmaf(fl[jj][in + 0], vu[0], av[jj]);
            av[jj] = fmaf(fl[jj][in + 1], vu[1], av[jj]);
            av[jj] = fmaf(fl[jj][in + 2], vu[2], av[jj]);
            av[jj] = fmaf(fl[jj][in + 3], vu[3], av[jj]);
        }
    }
    float bkv = bk[t];
    float bvv = bv[t];
#pragma unroll
    for (int jj = 0; jj < 4; jj++) {
        k_s[(unsigned)(j0 + jj) * DMODEL + t] = (unsigned short)f2bs((ak[jj] + bkv) * 0.0625f);
        vT[(unsigned)t * MSAMP + (j0 + jj)]   = (unsigned short)f2bs(av[jj] + bvv);
    }
}

// ---------------------------------------------------------------------------
// Fused q -> w -> res -> concat. 128-row tile per WG, 4 waves (2 row x 2 col),
// MFMA 16x16x32 bf16. Epilogue stages f32 res in LDS, coalesced [res|feat].
// [unchanged from R5]
// ---------------------------------------------------------------------------
#define QS  264
#define WSR 136
#define RS  258
#define MAIN_LDS (128 * RS * 4)   // 132096 B

__global__ __launch_bounds__(256, 1) void main_kernel(
    const float* __restrict__ feat,
    const float* __restrict__ Wq, const float* __restrict__ bq,
    const unsigned short* __restrict__ k_s,
    const unsigned short* __restrict__ vT,
    float* __restrict__ out)
{
    extern __shared__ char smem[];
    unsigned short* qlds = (unsigned short*)smem;
    unsigned short* wlds = (unsigned short*)(smem + 128 * QS * 2);

    const int tid  = threadIdx.x;
    const int ln   = tid & 63;
    const int wid  = tid >> 6;
    const int wr   = wid & 1;
    const int wc   = wid >> 1;
    const int r0   = blockIdx.x * 128;
    const int lrow = ln & 15;
    const int lk   = (ln >> 4) * 8;
    const int crow = (ln >> 4) * 4;

    const f32x4_t fzero = {0.f, 0.f, 0.f, 0.f};

    f32x4_t qa[4][8];
#pragma unroll
    for (int m = 0; m < 4; m++)
#pragma unroll
        for (int n = 0; n < 8; n++) qa[m][n] = fzero;

#pragma unroll
    for (int kb = 0; kb < DMODEL; kb += 32) {
        bf16x8_t A[4], B[8];
#pragma unroll
        for (int m = 0; m < 4; m++)
            A[m] = cvt8(feat + (size_t)(r0 + wr * 64 + m * 16 + lrow) * DMODEL + kb + lk);
#pragma unroll
        for (int n = 0; n < 8; n++)
            B[n] = cvt8(Wq + (size_t)(wc * 128 + n * 16 + lrow) * DMODEL + kb + lk);
#pragma unroll
        for (int m = 0; m < 4; m++)
#pragma unroll
            for (int n = 0; n < 8; n++)
                qa[m][n] = __builtin_amdgcn_mfma_f32_16x16x32_bf16(
                    A[m], B[n], qa[m][n], 0, 0, 0);
    }
#pragma unroll
    for (int n = 0; n < 8; n++) {
        float bqv = bq[wc * 128 + n * 16 + lrow];
#pragma unroll
        for (int m = 0; m < 4; m++)
#pragma unroll
            for (int r = 0; r < 4; r++)
                qlds[(wr * 64 + m * 16 + crow + r) * QS + wc * 128 + n * 16 + lrow] =
                    (unsigned short)f2bs(qa[m][n][r] + bqv);
    }
    __syncthreads();

    f32x4_t racc[4][8];
#pragma unroll
    for (int m = 0; m < 4; m++)
#pragma unroll
        for (int n = 0; n < 8; n++) racc[m][n] = fzero;

    for (int jb = 0; jb < 8; jb++) {
        f32x4_t wa[4][4];
#pragma unroll
        for (int m = 0; m < 4; m++)
#pragma unroll
            for (int n = 0; n < 4; n++) wa[m][n] = fzero;

#pragma unroll
        for (int kb = 0; kb < DMODEL; kb += 32) {
            bf16x8_t A[4], B[4];
#pragma unroll
            for (int m = 0; m < 4; m++)
                A[m] = *(const bf16x8_t*)(qlds + (wr * 64 + m * 16 + lrow) * QS + kb + lk);
#pragma unroll
            for (int n = 0; n < 4; n++)
                B[n] = *(const bf16x8_t*)(k_s +
                    (size_t)(jb * 128 + wc * 64 + n * 16 + lrow) * DMODEL + kb + lk);
#pragma unroll
            for (int m = 0; m < 4; m++)
#pragma unroll
                for (int n = 0; n < 4; n++)
                    wa[m][n] = __builtin_amdgcn_mfma_f32_16x16x32_bf16(
                        A[m], B[n], wa[m][n], 0, 0, 0);
        }
#pragma unroll
        for (int m = 0; m < 4; m++)
#pragma unroll
            for (int n = 0; n < 4; n++)
#pragma unroll
                for (int r = 0; r < 4; r++)
                    wlds[(wr * 64 + m * 16 + crow + r) * WSR + wc * 64 + n * 16 + lrow] =
                        (unsigned short)f2bs(wa[m][n][r]);
        __syncthreads();

#pragma unroll
        for (int kb2 = 0; kb2 < 128; kb2 += 32) {
            bf16x8_t A[4], B[8];
#pragma unroll
            for (int m = 0; m < 4; m++)
                A[m] = *(const bf16x8_t*)(wlds + (wr * 64 + m * 16 + lrow) * WSR + kb2 + lk);
#pragma unroll
            for (int n = 0; n < 8; n++)
                B[n] = *(const bf16x8_t*)(vT +
                    (size_t)(wc * 128 + n * 16 + lrow) * MSAMP + jb * 128 + kb2 + lk);
#pragma unroll
            for (int m = 0; m < 4; m++)
#pragma unroll
                for (int n = 0; n < 8; n++)
                    racc[m][n] = __builtin_amdgcn_mfma_f32_16x16x32_bf16(
                        A[m], B[n], racc[m][n], 0, 0, 0);
        }
        __syncthreads();
    }

    float* rlds = (float*)smem;
#pragma unroll
    for (int m = 0; m < 4; m++)
#pragma unroll
        for (int n = 0; n < 8; n++)
#pragma unroll
            for (int r = 0; r < 4; r++)
                rlds[(wr * 64 + m * 16 + crow + r) * RS + wc * 128 + n * 16 + lrow] =
                    racc[m][n][r];
    __syncthreads();

#pragma unroll
    for (int base = 0; base < 128; base += 4) {
        int row = base + wid;
        f32x4_t a = *(const f32x4_t*)(rlds + row * RS + ln * 4);
        f32x4_t b = *(const f32x4_t*)(feat + (size_t)(r0 + row) * DMODEL + ln * 4);
        *(f32x4_t*)(out + (size_t)(r0 + row) * 512 + ln * 4)       = a;
        *(f32x4_t*)(out + (size_t)(r0 + row) * 512 + 256 + ln * 4) = b;
    }
}

// ---------------------------------------------------------------------------
extern "C" void kernel_launch(void* const* d_in, const int* in_sizes, int n_in,
                              void* d_out, int out_size, void* d_ws, size_t ws_size,
                              hipStream_t stream) {
    const float* p_xyz = (const float*)d_in[0];
    const float* feat  = (const float*)d_in[1];
    const float* Wq    = (const float*)d_in[2];
    const float* bq    = (const float*)d_in[3];
    const float* Wk    = (const float*)d_in[4];
    const float* bk    = (const float*)d_in[5];
    const float* Wv    = (const float*)d_in[6];
    const float* bv    = (const float*)d_in[7];
    float* out = (float*)d_out;

    char* ws = (char*)d_ws;
    unsigned long long* slots = (unsigned long long*)ws;                //  16 KB [2][NW][SLW]
    int*                idx   = (int*)(ws + 16384);                     //   4 KB
    unsigned short*     k_s   = (unsigned short*)(ws + 32768);          // 512 KB
    unsigned short*     vT    = (unsigned short*)(ws + 32768 + 524288); // 512 KB

    hipMemsetAsync(d_ws, 0, 16384, stream);   // invalidate slots every call

    hipLaunchKernelGGL(fps_kernel, dim3(NW), dim3(64), 0, stream,
                       p_xyz, slots, idx);
    hipLaunchKernelGGL(kv_kernel, dim3(MSAMP / 4), dim3(256), 0, stream,
                       feat, Wk, bk, Wv, bv, idx, k_s, vT);
    hipFuncSetAttribute((const void*)main_kernel,
                        hipFuncAttributeMaxDynamicSharedMemorySize, MAIN_LDS);
    hipLaunchKernelGGL(main_kernel, dim3(N_PTS / 128), dim3(256), MAIN_LDS, stream,
                       feat, Wq, bq, k_s, vT, out);
}

// Round 9
// 1391.320 us; speedup vs baseline: 2.4071x; 1.5903x over previous
//
#include <hip/hip_runtime.h>
#include <hip/hip_bf16.h>

#define N_PTS  65536
#define DMODEL 256
#define MSAMP  1024

#define NW   64   // FPS waves = single-wave workgroups (all co-resident)
#define FPT  16   // points per lane: 65536 / (64 * 64)
#define SLW  16   // u64s per slot line: 128B stride, one wave per line
#define KMAX 8    // max emissions per rendezvous round

typedef short bf16x8_t __attribute__((ext_vector_type(8)));
typedef float f32x4_t  __attribute__((ext_vector_type(4)));

__device__ __forceinline__ short f2bs(float f) {
    __hip_bfloat16 h = __float2bfloat16(f);   // RNE
    return *reinterpret_cast<short*>(&h);
}

__device__ __forceinline__ bf16x8_t cvt8(const float* p) {
    f32x4_t a = *(const f32x4_t*)(p);
    f32x4_t b = *(const f32x4_t*)(p + 4);
    bf16x8_t r;
#pragma unroll
    for (int i = 0; i < 4; i++) { r[i] = f2bs(a[i]); r[i + 4] = f2bs(b[i]); }
    return r;
}

// exact numpy distance: per-op RN f32, ((dx^2+dy^2)+dz^2), no FMA
__device__ __forceinline__ float dist2(float ax, float ay, float az,
                                       float bx, float by, float bz) {
    float dx = __fsub_rn(ax, bx), dy = __fsub_rn(ay, by), dz = __fsub_rn(az, bz);
    return __fadd_rn(__fadd_rn(__fmul_rn(dx, dx), __fmul_rn(dy, dy)),
                     __fmul_rn(dz, dz));
}
// u64 max via f64 fmax (packs are positive f64 bit patterns; proven R5-R8)
__device__ __forceinline__ unsigned long long dmax64(unsigned long long a,
                                                     unsigned long long b) {
    double r = fmax(__longlong_as_double((long long)a),
                    __longlong_as_double((long long)b));
    return (unsigned long long)__double_as_longlong(r);
}
__device__ __forceinline__ unsigned long long bfly_max(unsigned long long v) {
    double dp = __longlong_as_double((long long)v);
#pragma unroll
    for (int s = 1; s < 64; s <<= 1)
        dp = fmax(dp, __shfl_xor(dp, s, 64));
    return (unsigned long long)__double_as_longlong(dp);
}

// ---------------------------------------------------------------------------
// Batched-candidate FPS. Per rendezvous round r:
//  1) apply pending winners to dd (exact numpy ops), build packs (val|invidx)
//  2) extract top-4 packs + 5th value bound B via 5 butterfly-argmax passes
//  3) publish 5 tagged u64s into the wave's private 128B line (R8 skeleton)
//  4) poll lane l <- wave l's line (tag-validated, sleep-throttled)
//  5) replay FPS on the 256-candidate pool, identically on every wave:
//     emission 1 unconditional (exact: every wave's #1 pack is present, pack
//     order = numpy first-index tie-break); emissions 2..k while updated best
//     value STRICTLY > maxB (unpublished points bounded by their wave's B;
//     candidate updates use the same exact arithmetic, so candidate values
//     equal true dd bitwise). >=1 emission/round -> no livelock; all waves
//     run identical code on identical data -> identical round count.
// ---------------------------------------------------------------------------
__global__ __launch_bounds__(64) void fps_kernel(
    const float*        __restrict__ xyz,      // (N,3) f32
    unsigned long long* __restrict__ slots,    // [2][NW][SLW] u64, zeroed per call
    int*                __restrict__ idx)      // (MSAMP) out
{
    const int l = threadIdx.x;       // 0..63
    const int g = blockIdx.x;        // 0..63
    const int base = g * (FPT * 64) + l;

    float px[FPT], py[FPT], pz[FPT], dd[FPT];
    unsigned long long inv[FPT];
#pragma unroll
    for (int i = 0; i < FPT; i++) {
        int p = base + i * 64;
        px[i] = xyz[3 * p + 0];
        py[i] = xyz[3 * p + 1];
        pz[i] = xyz[3 * p + 2];
        dd[i] = 1e10f;
        inv[i] = (unsigned long long)(0xFFFFu - (unsigned)p);
    }
    if (g == 0 && l == 0) idx[0] = 0;

    float wxl[KMAX], wyl[KMAX], wzl[KMAX];
    wxl[0] = xyz[0]; wyl[0] = xyz[1]; wzl[0] = xyz[2];   // pending: point 0
    int k = 1, total = 0, r = 0;

    while (total < MSAMP - 1) {
        ++r;
        // ---- 1) apply pending winners to dd (t-outer: uniform branch skip) --
#pragma unroll
        for (int t = 0; t < KMAX; t++) if (t < k) {
#pragma unroll
            for (int i = 0; i < FPT; i++)
                dd[i] = fminf(dd[i], dist2(px[i], py[i], pz[i],
                                           wxl[t], wyl[t], wzl[t]));
        }
        unsigned long long p[FPT];
#pragma unroll
        for (int i = 0; i < FPT; i++)
            p[i] = (((unsigned long long)__float_as_uint(dd[i])) << 32) | inv[i];

        // ---- 2) top-5 packs via 5 butterfly-argmax passes -------------------
        unsigned long long top[5];
#pragma unroll
        for (int t = 0; t < 5; t++) {
            unsigned long long lm = 0;
#pragma unroll
            for (int i = 0; i < FPT; i++) lm = dmax64(lm, p[i]);
            unsigned long long gt = bfly_max(lm);
            top[t] = gt;
#pragma unroll
            for (int i = 0; i < FPT; i++) p[i] = (p[i] == gt) ? 0ull : p[i];
        }

        // ---- 3) publish 5 tagged u64s (lanes 0-4) into own 128B line --------
        const int ph = r & 1;
        const unsigned rt = (unsigned)(r & 0xFFFF);
        unsigned long long sv = top[0];
        sv = (l == 1) ? top[1] : sv;
        sv = (l == 2) ? top[2] : sv;
        sv = (l == 3) ? top[3] : sv;
        sv = (l == 4) ? top[4] : sv;
        sv |= ((unsigned long long)rt) << 16;
        if (l < 5)
            __hip_atomic_store(slots + ((size_t)(ph * NW + g) * SLW + l), sv,
                               __ATOMIC_RELAXED, __HIP_MEMORY_SCOPE_AGENT);

        // ---- 4) poll: lane l reads wave l's 5 u64s, tag-validated -----------
        const unsigned long long* Q = slots + (size_t)ph * NW * SLW + (size_t)l * SLW;
        unsigned long long u0, u1, u2, u3, u4;
        for (;;) {
            u0 = __hip_atomic_load(Q + 0, __ATOMIC_RELAXED, __HIP_MEMORY_SCOPE_AGENT);
            u1 = __hip_atomic_load(Q + 1, __ATOMIC_RELAXED, __HIP_MEMORY_SCOPE_AGENT);
            u2 = __hip_atomic_load(Q + 2, __ATOMIC_RELAXED, __HIP_MEMORY_SCOPE_AGENT);
            u3 = __hip_atomic_load(Q + 3, __ATOMIC_RELAXED, __HIP_MEMORY_SCOPE_AGENT);
            u4 = __hip_atomic_load(Q + 4, __ATOMIC_RELAXED, __HIP_MEMORY_SCOPE_AGENT);
            bool ok = (((unsigned)(u0 >> 16) & 0xFFFFu) == rt) &
                      (((unsigned)(u1 >> 16) & 0xFFFFu) == rt) &
                      (((unsigned)(u2 >> 16) & 0xFFFFu) == rt) &
                      (((unsigned)(u3 >> 16) & 0xFFFFu) == rt) &
                      (((unsigned)(u4 >> 16) & 0xFFFFu) == rt);
            if (__all(ok)) break;
            __builtin_amdgcn_s_sleep(2);
        }

        // ---- parse: lane l holds wave l's 4 candidates + bound --------------
        float cv[4];
        unsigned ici[4];
        int ci[4];
        cv[0] = __uint_as_float((unsigned)(u0 >> 32)); ici[0] = (unsigned)(u0 & 0xFFFFu);
        cv[1] = __uint_as_float((unsigned)(u1 >> 32)); ici[1] = (unsigned)(u1 & 0xFFFFu);
        cv[2] = __uint_as_float((unsigned)(u2 >> 32)); ici[2] = (unsigned)(u2 & 0xFFFFu);
        cv[3] = __uint_as_float((unsigned)(u3 >> 32)); ici[3] = (unsigned)(u3 & 0xFFFFu);
#pragma unroll
        for (int c = 0; c < 4; c++) ci[c] = 0xFFFF - (int)ici[c];
        float Bv = __uint_as_float((unsigned)(u4 >> 32));

        float cx4[4], cy4[4], cz4[4];
#pragma unroll
        for (int c = 0; c < 4; c++) {
            cx4[c] = xyz[3 * ci[c] + 0];
            cy4[c] = xyz[3 * ci[c] + 1];
            cz4[c] = xyz[3 * ci[c] + 2];
        }
        float mB = Bv;
#pragma unroll
        for (int s = 1; s < 64; s <<= 1)
            mB = fmaxf(mB, __shfl_xor(mB, s, 64));

        // ---- 5) emission loop (identical on every wave) ---------------------
        int kk = 0;
        while (total < MSAMP - 1 && kk < KMAX) {
            unsigned long long lb = 0;
#pragma unroll
            for (int c = 0; c < 4; c++)
                lb = dmax64(lb, (((unsigned long long)__float_as_uint(cv[c])) << 32) | ici[c]);
            unsigned long long gb = bfly_max(lb);
            float gv = __uint_as_float((unsigned)(gb >> 32));
            if (kk > 0 && !(gv > mB)) break;     // strict >: exact vs unpublished

            int widx = 0xFFFF - (int)(gb & 0xFFFFu);
            if (g == 0 && l == 0) idx[total + 1] = widx;

            // winner coords from the owning lane (packs globally unique)
            float sx = cx4[0], sy = cy4[0], sz = cz4[0];
#pragma unroll
            for (int c = 1; c < 4; c++) {
                bool h = ((((unsigned long long)__float_as_uint(cv[c])) << 32) | ici[c]) == gb;
                sx = h ? cx4[c] : sx;
                sy = h ? cy4[c] : sy;
                sz = h ? cz4[c] : sz;
            }
            unsigned long long mo = __ballot(lb == gb);
            int ol = __ffsll((unsigned long long)mo) - 1;
            float wx = __shfl(sx, ol, 64);
            float wy = __shfl(sy, ol, 64);
            float wz = __shfl(sz, ol, 64);
#pragma unroll
            for (int t = 0; t < KMAX; t++) if (t == kk) { wxl[t] = wx; wyl[t] = wy; wzl[t] = wz; }

            // exact candidate updates (bitwise == true dd evolution)
#pragma unroll
            for (int c = 0; c < 4; c++)
                cv[c] = fminf(cv[c], dist2(cx4[c], cy4[c], cz4[c], wx, wy, wz));

            total++; kk++;
        }
        k = kk;
    }
}

// ---------------------------------------------------------------------------
// Gather + K/V projection in f32; outputs bf16. k pre-scaled by 1/16 (exact),
// row-major (j,k); v stored transposed (d,j).   [unchanged, proven]
// ---------------------------------------------------------------------------
__global__ __launch_bounds__(256) void kv_kernel(
    const float* __restrict__ feat,
    const float* __restrict__ Wk, const float* __restrict__ bk,
    const float* __restrict__ Wv, const float* __restrict__ bv,
    const int* __restrict__ idx,
    unsigned short* __restrict__ k_s,   // (MSAMP, DMODEL) bf16, * 1/16
    unsigned short* __restrict__ vT)    // (DMODEL, MSAMP) bf16
{
    __shared__ float fl[4][DMODEL];
    const int t  = threadIdx.x;
    const int j0 = blockIdx.x * 4;
    {
        int jj = t >> 6;
        int e  = (t & 63) * 4;
        int src = idx[j0 + jj];
        f32x4_t v = *(const f32x4_t*)(feat + (size_t)src * DMODEL + e);
        fl[jj][e + 0] = v[0];
        fl[jj][e + 1] = v[1];
        fl[jj][e + 2] = v[2];
        fl[jj][e + 3] = v[3];
    }
    __syncthreads();

    float ak[4] = {0.f, 0.f, 0.f, 0.f};
    float av[4] = {0.f, 0.f, 0.f, 0.f};
    const float* wkr = Wk + (size_t)t * DMODEL;
    const float* wvr = Wv + (size_t)t * DMODEL;
#pragma unroll 4
    for (int in = 0; in < DMODEL; in += 4) {
        f32x4_t ku = *(const f32x4_t*)(wkr + in);
        f32x4_t vu = *(const f32x4_t*)(wvr + in);
#pragma unroll
        for (int jj = 0; jj < 4; jj++) {
            ak[jj] = fmaf(fl[jj][in + 0], ku[0], ak[jj]);
            ak[jj] = fmaf(fl[jj][in + 1], ku[1], ak[jj]);
            ak[jj] = fmaf(fl[jj][in + 2], ku[2], ak[jj]);
            ak[jj] = fmaf(fl[jj][in + 3], ku[3], ak[jj]);
            av[jj] = fmaf(fl[jj][in + 0], vu[0], av[jj]);
            av[jj] = fmaf(fl[jj][in + 1], vu[1], av[jj]);
            av[jj] = fmaf(fl[jj][in + 2], vu[2], av[jj]);
            av[jj] = fmaf(fl[jj][in + 3], vu[3], av[jj]);
        }
    }
    float bkv = bk[t];
    float bvv = bv[t];
#pragma unroll
    for (int jj = 0; jj < 4; jj++) {
        k_s[(unsigned)(j0 + jj) * DMODEL + t] = (unsigned short)f2bs((ak[jj] + bkv) * 0.0625f);
        vT[(unsigned)t * MSAMP + (j0 + jj)]   = (unsigned short)f2bs(av[jj] + bvv);
    }
}

// ---------------------------------------------------------------------------
// Fused q -> w -> res -> concat. 128-row tile per WG, 4 waves (2 row x 2 col),
// MFMA 16x16x32 bf16. Epilogue stages f32 res in LDS, coalesced [res|feat].
// [unchanged, proven]
// ---------------------------------------------------------------------------
#define QS  264
#define WSR 136
#define RS  258
#define MAIN_LDS (128 * RS * 4)   // 132096 B

__global__ __launch_bounds__(256, 1) void main_kernel(
    const float* __restrict__ feat,
    const float* __restrict__ Wq, const float* __restrict__ bq,
    const unsigned short* __restrict__ k_s,
    const unsigned short* __restrict__ vT,
    float* __restrict__ out)
{
    extern __shared__ char smem[];
    unsigned short* qlds = (unsigned short*)smem;
    unsigned short* wlds = (unsigned short*)(smem + 128 * QS * 2);

    const int tid  = threadIdx.x;
    const int ln   = tid & 63;
    const int wid  = tid >> 6;
    const int wr   = wid & 1;
    const int wc   = wid >> 1;
    const int r0   = blockIdx.x * 128;
    const int lrow = ln & 15;
    const int lk   = (ln >> 4) * 8;
    const int crow = (ln >> 4) * 4;

    const f32x4_t fzero = {0.f, 0.f, 0.f, 0.f};

    f32x4_t qa[4][8];
#pragma unroll
    for (int m = 0; m < 4; m++)
#pragma unroll
        for (int n = 0; n < 8; n++) qa[m][n] = fzero;

#pragma unroll
    for (int kb = 0; kb < DMODEL; kb += 32) {
        bf16x8_t A[4], B[8];
#pragma unroll
        for (int m = 0; m < 4; m++)
            A[m] = cvt8(feat + (size_t)(r0 + wr * 64 + m * 16 + lrow) * DMODEL + kb + lk);
#pragma unroll
        for (int n = 0; n < 8; n++)
            B[n] = cvt8(Wq + (size_t)(wc * 128 + n * 16 + lrow) * DMODEL + kb + lk);
#pragma unroll
        for (int m = 0; m < 4; m++)
#pragma unroll
            for (int n = 0; n < 8; n++)
                qa[m][n] = __builtin_amdgcn_mfma_f32_16x16x32_bf16(
                    A[m], B[n], qa[m][n], 0, 0, 0);
    }
#pragma unroll
    for (int n = 0; n < 8; n++) {
        float bqv = bq[wc * 128 + n * 16 + lrow];
#pragma unroll
        for (int m = 0; m < 4; m++)
#pragma unroll
            for (int r = 0; r < 4; r++)
                qlds[(wr * 64 + m * 16 + crow + r) * QS + wc * 128 + n * 16 + lrow] =
                    (unsigned short)f2bs(qa[m][n][r] + bqv);
    }
    __syncthreads();

    f32x4_t racc[4][8];
#pragma unroll
    for (int m = 0; m < 4; m++)
#pragma unroll
        for (int n = 0; n < 8; n++) racc[m][n] = fzero;

    for (int jb = 0; jb < 8; jb++) {
        f32x4_t wa[4][4];
#pragma unroll
        for (int m = 0; m < 4; m++)
#pragma unroll
            for (int n = 0; n < 4; n++) wa[m][n] = fzero;

#pragma unroll
        for (int kb = 0; kb < DMODEL; kb += 32) {
            bf16x8_t A[4], B[4];
#pragma unroll
            for (int m = 0; m < 4; m++)
                A[m] = *(const bf16x8_t*)(qlds + (wr * 64 + m * 16 + lrow) * QS + kb + lk);
#pragma unroll
            for (int n = 0; n < 4; n++)
                B[n] = *(const bf16x8_t*)(k_s +
                    (size_t)(jb * 128 + wc * 64 + n * 16 + lrow) * DMODEL + kb + lk);
#pragma unroll
            for (int m = 0; m < 4; m++)
#pragma unroll
                for (int n = 0; n < 4; n++)
                    wa[m][n] = __builtin_amdgcn_mfma_f32_16x16x32_bf16(
                        A[m], B[n], wa[m][n], 0, 0, 0);
        }
#pragma unroll
        for (int m = 0; m < 4; m++)
#pragma unroll
            for (int n = 0; n < 4; n++)
#pragma unroll
                for (int r = 0; r < 4; r++)
                    wlds[(wr * 64 + m * 16 + crow + r) * WSR + wc * 64 + n * 16 + lrow] =
                        (unsigned short)f2bs(wa[m][n][r]);
        __syncthreads();

#pragma unroll
        for (int kb2 = 0; kb2 < 128; kb2 += 32) {
            bf16x8_t A[4], B[8];
#pragma unroll
            for (int m = 0; m < 4; m++)
                A[m] = *(const bf16x8_t*)(wlds + (wr * 64 + m * 16 + lrow) * WSR + kb2 + lk);
#pragma unroll
            for (int n = 0; n < 8; n++)
                B[n] = *(const bf16x8_t*)(vT +
                    (size_t)(wc * 128 + n * 16 + lrow) * MSAMP + jb * 128 + kb2 + lk);
#pragma unroll
            for (int m = 0; m < 4; m++)
#pragma unroll
                for (int n = 0; n < 8; n++)
                    racc[m][n] = __builtin_amdgcn_mfma_f32_16x16x32_bf16(
                        A[m], B[n], racc[m][n], 0, 0, 0);
        }
        __syncthreads();
    }

    float* rlds = (float*)smem;
#pragma unroll
    for (int m = 0; m < 4; m++)
#pragma unroll
        for (int n = 0; n < 8; n++)
#pragma unroll
            for (int r = 0; r < 4; r++)
                rlds[(wr * 64 + m * 16 + crow + r) * RS + wc * 128 + n * 16 + lrow] =
                    racc[m][n][r];
    __syncthreads();

#pragma unroll
    for (int base = 0; base < 128; base += 4) {
        int row = base + wid;
        f32x4_t a = *(const f32x4_t*)(rlds + row * RS + ln * 4);
        f32x4_t b = *(const f32x4_t*)(feat + (size_t)(r0 + row) * DMODEL + ln * 4);
        *(f32x4_t*)(out + (size_t)(r0 + row) * 512 + ln * 4)       = a;
        *(f32x4_t*)(out + (size_t)(r0 + row) * 512 + 256 + ln * 4) = b;
    }
}

// ---------------------------------------------------------------------------
extern "C" void kernel_launch(void* const* d_in, const int* in_sizes, int n_in,
                              void* d_out, int out_size, void* d_ws, size_t ws_size,
                              hipStream_t stream) {
    const float* p_xyz = (const float*)d_in[0];
    const float* feat  = (const float*)d_in[1];
    const float* Wq    = (const float*)d_in[2];
    const float* bq    = (const float*)d_in[3];
    const float* Wk    = (const float*)d_in[4];
    const float* bk    = (const float*)d_in[5];
    const float* Wv    = (const float*)d_in[6];
    const float* bv    = (const float*)d_in[7];
    float* out = (float*)d_out;

    char* ws = (char*)d_ws;
    unsigned long long* slots = (unsigned long long*)ws;                //  16 KB [2][NW][SLW]
    int*                idx   = (int*)(ws + 16384);                     //   4 KB
    unsigned short*     k_s   = (unsigned short*)(ws + 32768);          // 512 KB
    unsigned short*     vT    = (unsigned short*)(ws + 32768 + 524288); // 512 KB

    hipMemsetAsync(d_ws, 0, 16384, stream);   // invalidate slots every call

    hipLaunchKernelGGL(fps_kernel, dim3(NW), dim3(64), 0, stream,
                       p_xyz, slots, idx);
    hipLaunchKernelGGL(kv_kernel, dim3(MSAMP / 4), dim3(256), 0, stream,
                       feat, Wk, bk, Wv, bv, idx, k_s, vT);
    hipFuncSetAttribute((const void*)main_kernel,
                        hipFuncAttributeMaxDynamicSharedMemorySize, MAIN_LDS);
    hipLaunchKernelGGL(main_kernel, dim3(N_PTS / 128), dim3(256), MAIN_LDS, stream,
                       feat, Wq, bq, k_s, vT, out);
}

// Round 10
// 1095.538 us; speedup vs baseline: 3.0570x; 1.2700x over previous
//
#include <hip/hip_runtime.h>
#include <hip/hip_bf16.h>

#define N_PTS  65536
#define DMODEL 256
#define MSAMP  1024

#define NW    64   // FPS waves = single-wave workgroups (all co-resident)
#define FPT   16   // points per lane: 65536 / (64 * 64)
#define SLW   16   // u64s per slot line: 128B stride, one wave per line
#define NCAND 8    // candidates published per wave (+1 bound slot)

typedef short bf16x8_t __attribute__((ext_vector_type(8)));
typedef float f32x4_t  __attribute__((ext_vector_type(4)));

__device__ __forceinline__ short f2bs(float f) {
    __hip_bfloat16 h = __float2bfloat16(f);   // RNE
    return *reinterpret_cast<short*>(&h);
}

__device__ __forceinline__ bf16x8_t cvt8(const float* p) {
    f32x4_t a = *(const f32x4_t*)(p);
    f32x4_t b = *(const f32x4_t*)(p + 4);
    bf16x8_t r;
#pragma unroll
    for (int i = 0; i < 4; i++) { r[i] = f2bs(a[i]); r[i + 4] = f2bs(b[i]); }
    return r;
}

// exact numpy distance: per-op RN f32, ((dx^2+dy^2)+dz^2), no FMA
__device__ __forceinline__ float dist2(float ax, float ay, float az,
                                       float bx, float by, float bz) {
    float dx = __fsub_rn(ax, bx), dy = __fsub_rn(ay, by), dz = __fsub_rn(az, bz);
    return __fadd_rn(__fadd_rn(__fmul_rn(dx, dx), __fmul_rn(dy, dy)),
                     __fmul_rn(dz, dz));
}
// u64 max via f64 fmax (packs are positive f64 bit patterns; proven R5-R9)
__device__ __forceinline__ unsigned long long dmax64(unsigned long long a,
                                                     unsigned long long b) {
    double r = fmax(__longlong_as_double((long long)a),
                    __longlong_as_double((long long)b));
    return (unsigned long long)__double_as_longlong(r);
}
__device__ __forceinline__ unsigned long long bfly_max(unsigned long long v) {
    double dp = __longlong_as_double((long long)v);
#pragma unroll
    for (int s = 1; s < 64; s <<= 1)
        dp = fmax(dp, __shfl_xor(dp, s, 64));
    return (unsigned long long)__double_as_longlong(dp);
}

// ---------------------------------------------------------------------------
// Batched-candidate FPS, NCAND=8 + uncapped emissions (R9 skeleton, proven).
// Per rendezvous round r:
//  1) build packs (dd|invidx), extract top-9 via 9 fused zero+scan butterfly
//     passes (packs globally unique: distinct invidx)
//  2) publish 8 candidate packs + 9th-value bound, tagged, into the wave's
//     private 128B line; poll lane l <- wave l's line (tag-validated)
//  3) emission replay, identical on every wave: emission 1 unconditional
//     (global argmax is some wave's #1, pack order = numpy value-then-
//     smallest-index); further emissions while updated best STRICTLY > maxB
//     (unpublished points bounded by their wave's static 9th value; min-
//     updates are order-exact). Winner's coords shfl'd from the owning lane;
//     each emission updates candidate values AND local dd with the exact
//     numpy min-sequence. Winner self-distance = 0 removes it from the pool.
//  >=1 emission/round -> no livelock; identical control flow on every wave.
// ---------------------------------------------------------------------------
__global__ __launch_bounds__(64) void fps_kernel(
    const float*        __restrict__ xyz,      // (N,3) f32
    unsigned long long* __restrict__ slots,    // [2][NW][SLW] u64, zeroed per call
    int*                __restrict__ idx)      // (MSAMP) out
{
    const int l = threadIdx.x;       // 0..63
    const int g = blockIdx.x;        // 0..63
    const int base = g * (FPT * 64) + l;

    float px[FPT], py[FPT], pz[FPT], dd[FPT];
    unsigned long long ivi[FPT];
    const float c0x = xyz[0], c0y = xyz[1], c0z = xyz[2];   // winner 0 = point 0
#pragma unroll
    for (int i = 0; i < FPT; i++) {
        int p = base + i * 64;
        px[i] = xyz[3 * p + 0];
        py[i] = xyz[3 * p + 1];
        pz[i] = xyz[3 * p + 2];
        dd[i] = fminf(1e10f, dist2(px[i], py[i], pz[i], c0x, c0y, c0z));
        ivi[i] = (unsigned long long)(0xFFFFu - (unsigned)p);
    }
    if (g == 0 && l == 0) idx[0] = 0;

    int total = 0, r = 0;
    while (total < MSAMP - 1) {
        ++r;
        // ---- 1) extract top-(NCAND+1) packs ------------------------------
        unsigned long long pk[FPT];
#pragma unroll
        for (int i = 0; i < FPT; i++)
            pk[i] = (((unsigned long long)__float_as_uint(dd[i])) << 32) | ivi[i];

        unsigned long long top[NCAND + 1];
        unsigned long long prev = ~0ull;            // matches no pack
#pragma unroll
        for (int t = 0; t < NCAND + 1; t++) {
            unsigned long long lm = 0;
#pragma unroll
            for (int i = 0; i < FPT; i++) {
                pk[i] = (pk[i] == prev) ? 0ull : pk[i];
                lm = dmax64(lm, pk[i]);
            }
            unsigned long long gt = bfly_max(lm);
            top[t] = gt;
            prev = gt;
        }

        // ---- 2) publish (lanes 0..NCAND) + poll --------------------------
        const int ph = r & 1;
        const unsigned rt = (unsigned)(r & 0xFFFF);
        unsigned long long sv = top[0];
#pragma unroll
        for (int t = 1; t <= NCAND; t++) sv = (l == t) ? top[t] : sv;
        sv |= ((unsigned long long)rt) << 16;       // bits 16-31 free in packs
        if (l <= NCAND)
            __hip_atomic_store(slots + ((size_t)(ph * NW + g) * SLW + l), sv,
                               __ATOMIC_RELAXED, __HIP_MEMORY_SCOPE_AGENT);

        const unsigned long long* Q = slots + (size_t)ph * NW * SLW + (size_t)l * SLW;
        unsigned long long u[NCAND + 1];
        for (;;) {
            bool ok = true;
#pragma unroll
            for (int t = 0; t <= NCAND; t++) {
                u[t] = __hip_atomic_load(Q + t, __ATOMIC_RELAXED,
                                         __HIP_MEMORY_SCOPE_AGENT);
                ok &= (((unsigned)(u[t] >> 16) & 0xFFFFu) == rt);
            }
            if (__all(ok)) break;
            __builtin_amdgcn_s_sleep(2);
        }

        // ---- parse: lane l holds wave l's 8 candidates + bound -----------
        float cv[NCAND], cxc[NCAND], cyc[NCAND], czc[NCAND];
        unsigned ici[NCAND];
#pragma unroll
        for (int c = 0; c < NCAND; c++) {
            cv[c]  = __uint_as_float((unsigned)(u[c] >> 32));
            ici[c] = (unsigned)(u[c] & 0xFFFFu);
            int pi = 0xFFFF - (int)ici[c];
            cxc[c] = xyz[3 * pi + 0];
            cyc[c] = xyz[3 * pi + 1];
            czc[c] = xyz[3 * pi + 2];
        }
        float mB = __uint_as_float((unsigned)(u[NCAND] >> 32));
#pragma unroll
        for (int s = 1; s < 64; s <<= 1)
            mB = fmaxf(mB, __shfl_xor(mB, s, 64));

        // ---- 3) emission loop (identical on every wave) ------------------
        int kk = 0;
        while (total < MSAMP - 1) {
            unsigned long long lb = 0;
#pragma unroll
            for (int c = 0; c < NCAND; c++)
                lb = dmax64(lb, (((unsigned long long)__float_as_uint(cv[c])) << 32) | ici[c]);
            unsigned long long gb = bfly_max(lb);
            float gv = __uint_as_float((unsigned)(gb >> 32));
            if (kk > 0 && !(gv > mB)) break;     // strict >: exact vs unpublished

            int widx = 0xFFFF - (int)(gb & 0xFFFFu);
            if (g == 0 && l == 0) idx[total + 1] = widx;

            // winner coords from the owning lane (packs globally unique)
            float sx = cxc[0], sy = cyc[0], sz = czc[0];
#pragma unroll
            for (int c = 1; c < NCAND; c++) {
                bool h = ((((unsigned long long)__float_as_uint(cv[c])) << 32) | ici[c]) == gb;
                sx = h ? cxc[c] : sx;
                sy = h ? cyc[c] : sy;
                sz = h ? czc[c] : sz;
            }
            unsigned long long mo = __ballot(lb == gb);
            int ol = __ffsll((unsigned long long)mo) - 1;
            float wx = __shfl(sx, ol, 64);
            float wy = __shfl(sy, ol, 64);
            float wz = __shfl(sz, ol, 64);

            // exact min-sequence updates: candidates AND local points
#pragma unroll
            for (int c = 0; c < NCAND; c++)
                cv[c] = fminf(cv[c], dist2(cxc[c], cyc[c], czc[c], wx, wy, wz));
#pragma unroll
            for (int i = 0; i < FPT; i++)
                dd[i] = fminf(dd[i], dist2(px[i], py[i], pz[i], wx, wy, wz));

            total++; kk++;
        }
    }
}

// ---------------------------------------------------------------------------
// Gather + K/V projection in f32; outputs bf16. k pre-scaled by 1/16 (exact),
// row-major (j,k); v stored transposed (d,j).   [unchanged, proven]
// ---------------------------------------------------------------------------
__global__ __launch_bounds__(256) void kv_kernel(
    const float* __restrict__ feat,
    const float* __restrict__ Wk, const float* __restrict__ bk,
    const float* __restrict__ Wv, const float* __restrict__ bv,
    const int* __restrict__ idx,
    unsigned short* __restrict__ k_s,   // (MSAMP, DMODEL) bf16, * 1/16
    unsigned short* __restrict__ vT)    // (DMODEL, MSAMP) bf16
{
    __shared__ float fl[4][DMODEL];
    const int t  = threadIdx.x;
    const int j0 = blockIdx.x * 4;
    {
        int jj = t >> 6;
        int e  = (t & 63) * 4;
        int src = idx[j0 + jj];
        f32x4_t v = *(const f32x4_t*)(feat + (size_t)src * DMODEL + e);
        fl[jj][e + 0] = v[0];
        fl[jj][e + 1] = v[1];
        fl[jj][e + 2] = v[2];
        fl[jj][e + 3] = v[3];
    }
    __syncthreads();

    float ak[4] = {0.f, 0.f, 0.f, 0.f};
    float av[4] = {0.f, 0.f, 0.f, 0.f};
    const float* wkr = Wk + (size_t)t * DMODEL;
    const float* wvr = Wv + (size_t)t * DMODEL;
#pragma unroll 4
    for (int in = 0; in < DMODEL; in += 4) {
        f32x4_t ku = *(const f32x4_t*)(wkr + in);
        f32x4_t vu = *(const f32x4_t*)(wvr + in);
#pragma unroll
        for (int jj = 0; jj < 4; jj++) {
            ak[jj] = fmaf(fl[jj][in + 0], ku[0], ak[jj]);
            ak[jj] = fmaf(fl[jj][in + 1], ku[1], ak[jj]);
            ak[jj] = fmaf(fl[jj][in + 2], ku[2], ak[jj]);
            ak[jj] = fmaf(fl[jj][in + 3], ku[3], ak[jj]);
            av[jj] = fmaf(fl[jj][in + 0], vu[0], av[jj]);
            av[jj] = fmaf(fl[jj][in + 1], vu[1], av[jj]);
            av[jj] = fmaf(fl[jj][in + 2], vu[2], av[jj]);
            av[jj] = fmaf(fl[jj][in + 3], vu[3], av[jj]);
        }
    }
    float bkv = bk[t];
    float bvv = bv[t];
#pragma unroll
    for (int jj = 0; jj < 4; jj++) {
        k_s[(unsigned)(j0 + jj) * DMODEL + t] = (unsigned short)f2bs((ak[jj] + bkv) * 0.0625f);
        vT[(unsigned)t * MSAMP + (j0 + jj)]   = (unsigned short)f2bs(av[jj] + bvv);
    }
}

// ---------------------------------------------------------------------------
// Fused q -> w -> res -> concat. 128-row tile per WG, 4 waves (2 row x 2 col),
// MFMA 16x16x32 bf16. Epilogue stages f32 res in LDS, coalesced [res|feat].
// [unchanged, proven]
// ---------------------------------------------------------------------------
#define QS  264
#define WSR 136
#define RS  258
#define MAIN_LDS (128 * RS * 4)   // 132096 B

__global__ __launch_bounds__(256, 1) void main_kernel(
    const float* __restrict__ feat,
    const float* __restrict__ Wq, const float* __restrict__ bq,
    const unsigned short* __restrict__ k_s,
    const unsigned short* __restrict__ vT,
    float* __restrict__ out)
{
    extern __shared__ char smem[];
    unsigned short* qlds = (unsigned short*)smem;
    unsigned short* wlds = (unsigned short*)(smem + 128 * QS * 2);

    const int tid  = threadIdx.x;
    const int ln   = tid & 63;
    const int wid  = tid >> 6;
    const int wr   = wid & 1;
    const int wc   = wid >> 1;
    const int r0   = blockIdx.x * 128;
    const int lrow = ln & 15;
    const int lk   = (ln >> 4) * 8;
    const int crow = (ln >> 4) * 4;

    const f32x4_t fzero = {0.f, 0.f, 0.f, 0.f};

    f32x4_t qa[4][8];
#pragma unroll
    for (int m = 0; m < 4; m++)
#pragma unroll
        for (int n = 0; n < 8; n++) qa[m][n] = fzero;

#pragma unroll
    for (int kb = 0; kb < DMODEL; kb += 32) {
        bf16x8_t A[4], B[8];
#pragma unroll
        for (int m = 0; m < 4; m++)
            A[m] = cvt8(feat + (size_t)(r0 + wr * 64 + m * 16 + lrow) * DMODEL + kb + lk);
#pragma unroll
        for (int n = 0; n < 8; n++)
            B[n] = cvt8(Wq + (size_t)(wc * 128 + n * 16 + lrow) * DMODEL + kb + lk);
#pragma unroll
        for (int m = 0; m < 4; m++)
#pragma unroll
            for (int n = 0; n < 8; n++)
                qa[m][n] = __builtin_amdgcn_mfma_f32_16x16x32_bf16(
                    A[m], B[n], qa[m][n], 0, 0, 0);
    }
#pragma unroll
    for (int n = 0; n < 8; n++) {
        float bqv = bq[wc * 128 + n * 16 + lrow];
#pragma unroll
        for (int m = 0; m < 4; m++)
#pragma unroll
            for (int r = 0; r < 4; r++)
                qlds[(wr * 64 + m * 16 + crow + r) * QS + wc * 128 + n * 16 + lrow] =
                    (unsigned short)f2bs(qa[m][n][r] + bqv);
    }
    __syncthreads();

    f32x4_t racc[4][8];
#pragma unroll
    for (int m = 0; m < 4; m++)
#pragma unroll
        for (int n = 0; n < 8; n++) racc[m][n] = fzero;

    for (int jb = 0; jb < 8; jb++) {
        f32x4_t wa[4][4];
#pragma unroll
        for (int m = 0; m < 4; m++)
#pragma unroll
            for (int n = 0; n < 4; n++) wa[m][n] = fzero;

#pragma unroll
        for (int kb = 0; kb < DMODEL; kb += 32) {
            bf16x8_t A[4], B[4];
#pragma unroll
            for (int m = 0; m < 4; m++)
                A[m] = *(const bf16x8_t*)(qlds + (wr * 64 + m * 16 + lrow) * QS + kb + lk);
#pragma unroll
            for (int n = 0; n < 4; n++)
                B[n] = *(const bf16x8_t*)(k_s +
                    (size_t)(jb * 128 + wc * 64 + n * 16 + lrow) * DMODEL + kb + lk);
#pragma unroll
            for (int m = 0; m < 4; m++)
#pragma unroll
                for (int n = 0; n < 4; n++)
                    wa[m][n] = __builtin_amdgcn_mfma_f32_16x16x32_bf16(
                        A[m], B[n], wa[m][n], 0, 0, 0);
        }
#pragma unroll
        for (int m = 0; m < 4; m++)
#pragma unroll
            for (int n = 0; n < 4; n++)
#pragma unroll
                for (int r = 0; r < 4; r++)
                    wlds[(wr * 64 + m * 16 + crow + r) * WSR + wc * 64 + n * 16 + lrow] =
                        (unsigned short)f2bs(wa[m][n][r]);
        __syncthreads();

#pragma unroll
        for (int kb2 = 0; kb2 < 128; kb2 += 32) {
            bf16x8_t A[4], B[8];
#pragma unroll
            for (int m = 0; m < 4; m++)
                A[m] = *(const bf16x8_t*)(wlds + (wr * 64 + m * 16 + lrow) * WSR + kb2 + lk);
#pragma unroll
            for (int n = 0; n < 8; n++)
                B[n] = *(const bf16x8_t*)(vT +
                    (size_t)(wc * 128 + n * 16 + lrow) * MSAMP + jb * 128 + kb2 + lk);
#pragma unroll
            for (int m = 0; m < 4; m++)
#pragma unroll
                for (int n = 0; n < 8; n++)
                    racc[m][n] = __builtin_amdgcn_mfma_f32_16x16x32_bf16(
                        A[m], B[n], racc[m][n], 0, 0, 0);
        }
        __syncthreads();
    }

    float* rlds = (float*)smem;
#pragma unroll
    for (int m = 0; m < 4; m++)
#pragma unroll
        for (int n = 0; n < 8; n++)
#pragma unroll
            for (int r = 0; r < 4; r++)
                rlds[(wr * 64 + m * 16 + crow + r) * RS + wc * 128 + n * 16 + lrow] =
                    racc[m][n][r];
    __syncthreads();

#pragma unroll
    for (int base = 0; base < 128; base += 4) {
        int row = base + wid;
        f32x4_t a = *(const f32x4_t*)(rlds + row * RS + ln * 4);
        f32x4_t b = *(const f32x4_t*)(feat + (size_t)(r0 + row) * DMODEL + ln * 4);
        *(f32x4_t*)(out + (size_t)(r0 + row) * 512 + ln * 4)       = a;
        *(f32x4_t*)(out + (size_t)(r0 + row) * 512 + 256 + ln * 4) = b;
    }
}

// ---------------------------------------------------------------------------
extern "C" void kernel_launch(void* const* d_in, const int* in_sizes, int n_in,
                              void* d_out, int out_size, void* d_ws, size_t ws_size,
                              hipStream_t stream) {
    const float* p_xyz = (const float*)d_in[0];
    const float* feat  = (const float*)d_in[1];
    const float* Wq    = (const float*)d_in[2];
    const float* bq    = (const float*)d_in[3];
    const float* Wk    = (const float*)d_in[4];
    const float* bk    = (const float*)d_in[5];
    const float* Wv    = (const float*)d_in[6];
    const float* bv    = (const float*)d_in[7];
    float* out = (float*)d_out;

    char* ws = (char*)d_ws;
    unsigned long long* slots = (unsigned long long*)ws;                //  16 KB [2][NW][SLW]
    int*                idx   = (int*)(ws + 16384);                     //   4 KB
    unsigned short*     k_s   = (unsigned short*)(ws + 32768);          // 512 KB
    unsigned short*     vT    = (unsigned short*)(ws + 32768 + 524288); // 512 KB

    hipMemsetAsync(d_ws, 0, 16384, stream);   // invalidate slots every call

    hipLaunchKernelGGL(fps_kernel, dim3(NW), dim3(64), 0, stream,
                       p_xyz, slots, idx);
    hipLaunchKernelGGL(kv_kernel, dim3(MSAMP / 4), dim3(256), 0, stream,
                       feat, Wk, bk, Wv, bv, idx, k_s, vT);
    hipFuncSetAttribute((const void*)main_kernel,
                        hipFuncAttributeMaxDynamicSharedMemorySize, MAIN_LDS);
    hipLaunchKernelGGL(main_kernel, dim3(N_PTS / 128), dim3(256), MAIN_LDS, stream,
                       feat, Wq, bq, k_s, vT, out);
}